// Round 10
// baseline (135.123 us; speedup 1.0000x reference)
//
#include <hip/hip_runtime.h>
#include <math.h>

namespace {

constexpr int B  = 8;
constexpr int N  = 6;
constexpr int D  = 41;
constexpr int FH = 8;    // 128/16
constexpr int FW = 22;   // 352/16
constexpr int C  = 64;
constexpr int NPTS = B * N * D * FH * FW;   // 346368 = 1353 * 256
constexpr int NX0 = 200, NX1 = 200, NX2 = 1;
constexpr int NVOX = NX0 * NX1;             // 40000 voxels per batch (gz==0)
constexpr int MAT_STRIDE = 24;
constexpr int VTILES = NVOX / 64;           // 625 tiles per batch
constexpr int NTILES = B * VTILES;          // 5000
constexpr int CAP    = 4096;                // bin capacity per tile (ints)
constexpr int OUT4   = B * C * NVOX / 4;    // 5,120,000 float4s in out

__device__ inline void inv3x3(const float a[9], float r[9]) {
  float c00 = a[4] * a[8] - a[5] * a[7];
  float c01 = a[5] * a[6] - a[3] * a[8];
  float c02 = a[3] * a[7] - a[4] * a[6];
  float det = a[0] * c00 + a[1] * c01 + a[2] * c02;
  float id  = 1.0f / det;
  r[0] = c00 * id;
  r[1] = (a[2] * a[7] - a[1] * a[8]) * id;
  r[2] = (a[1] * a[5] - a[2] * a[4]) * id;
  r[3] = c01 * id;
  r[4] = (a[0] * a[8] - a[2] * a[6]) * id;
  r[5] = (a[2] * a[3] - a[0] * a[5]) * id;
  r[6] = c02 * id;
  r[7] = (a[1] * a[6] - a[0] * a[7]) * id;
  r[8] = (a[0] * a[4] - a[1] * a[3]) * id;
}

__device__ inline void build_mats(int i,
                                  const float* __restrict__ rots,
                                  const float* __restrict__ trans,
                                  const float* __restrict__ intrins,
                                  const float* __restrict__ post_rots,
                                  const float* __restrict__ post_trans,
                                  float* __restrict__ o) {
#pragma clang fp contract(off)
  const float eps = 1e-6f;
  float m[9], inv_post[9], ki[9];

  for (int k = 0; k < 9; ++k) m[k] = post_rots[i * 9 + k];
  m[0] += eps; m[4] += eps; m[8] += eps;
  inv3x3(m, inv_post);

  for (int k = 0; k < 9; ++k) m[k] = intrins[i * 9 + k];
  m[0] += eps; m[4] += eps; m[8] += eps;
  inv3x3(m, ki);

  for (int k = 0; k < 9; ++k) o[k] = inv_post[k];
  for (int r = 0; r < 3; ++r)
    for (int c = 0; c < 3; ++c)
      o[9 + r * 3 + c] = rots[i * 9 + r * 3 + 0] * ki[0 * 3 + c]
                       + rots[i * 9 + r * 3 + 1] * ki[1 * 3 + c]
                       + rots[i * 9 + r * 3 + 2] * ki[2 * 3 + c];
  for (int k = 0; k < 3; ++k) o[18 + k] = trans[i * 3 + k];
  for (int k = 0; k < 3; ++k) o[21 + k] = post_trans[i * 3 + k];
}

__device__ inline int point_voxel(int wid, const float* __restrict__ mats) {
#pragma clang fp contract(off)
  int t  = wid;
  int w  = t % FW;  t /= FW;
  int h  = t % FH;  t /= FH;
  int dd = t % D;   t /= D;
  int n  = t % N;
  int b  = t / N;

  const float* M = mats + (b * N + n) * MAT_STRIDE;

  float u   = (float)w * (351.0f / 21.0f);
  float v   = (float)h * (127.0f / 7.0f);
  float dep = 4.0f + (float)dd;

  float p0 = u - M[21], p1 = v - M[22], p2 = dep - M[23];

  float q0 = M[0] * p0 + M[1] * p1 + M[2] * p2;
  float q1 = M[3] * p0 + M[4] * p1 + M[5] * p2;
  float q2 = M[6] * p0 + M[7] * p1 + M[8] * p2;

  float sd;
  if (fabsf(q2) < 1e-6f) {
    float t2 = q2 + 1e-6f;
    float s  = (t2 > 0.0f) ? 1.0f : ((t2 < 0.0f) ? -1.0f : 0.0f);
    sd = 1e-6f * s;
  } else {
    sd = q2;
  }
  float r0 = q0 * sd, r1 = q1 * sd, r2 = sd;

  float g0 = (M[9]  * r0 + M[10] * r1 + M[11] * r2) + M[18];
  float g1 = (M[12] * r0 + M[13] * r1 + M[14] * r2) + M[19];
  float g2 = (M[15] * r0 + M[16] * r1 + M[17] * r2) + M[20];

  float gnx = (g0 + 50.0f) / 0.5f;
  float gny = (g1 + 50.0f) / 0.5f;
  float gnz = (g2 + 10.0f) / 20.0f;
  int gx = (int)gnx;
  int gy = (int)gny;
  int gz = (int)gnz;

  if (gx < 0 || gx >= NX0 || gy < 0 || gy >= NX1 || gz < 0 || gz >= NX2)
    return -1;
  return b * NVOX + gx * NX1 + gy;   // global voxel id (gz == 0)
}

// Pass 0: clear per-tile counts + overflow counter (5001 ints).
__global__ __launch_bounds__(256) void clear_counts(int* __restrict__ counts) {
  int i = blockIdx.x * 256 + threadIdx.x;
  if (i <= NTILES) counts[i] = 0;
}

// Pass 1: bin kept points by output tile AND zero `out` with a linear
// grid-stride float4 stream (82 MB at full BW, overlapped with the binning
// compute). Empty tiles are then never touched again.
__global__ __launch_bounds__(256) void bin_zero(const float* __restrict__ rots,
                                                const float* __restrict__ trans,
                                                const float* __restrict__ intrins,
                                                const float* __restrict__ post_rots,
                                                const float* __restrict__ post_trans,
                                                int* __restrict__ counts,
                                                int* __restrict__ bins,
                                                int* __restrict__ ovf,
                                                float4* __restrict__ out4) {
  __shared__ float smats[B * N * MAT_STRIDE];
  int t = threadIdx.x;
  if (t < B * N)
    build_mats(t, rots, trans, intrins, post_rots, post_trans, smats + t * MAT_STRIDE);
  __syncthreads();

  int pid = blockIdx.x * 256 + t;           // NPTS is a multiple of 256
  int v = point_voxel(pid, smats);
  if (v >= 0) {
    int bt  = v >> 6;                       // tile id (NVOX % 64 == 0)
    int vin = v & 63;
    int idx = atomicAdd(&counts[bt], 1);
    if (idx < CAP) {
      bins[(size_t)bt * CAP + idx] = pid | (vin << 19);
    } else {
      int o = atomicAdd(&counts[NTILES], 1);  // overflow counter
      if (o < NPTS) ovf[o] = pid;
    }
  }

  // linear zero of out: 5,120,000 float4s over 346,368 threads (15 iters)
  const float4 z = make_float4(0.f, 0.f, 0.f, 0.f);
  for (int i = pid; i < OUT4; i += NPTS) out4[i] = z;
}

// Pass 2: one small fire-and-retire block per tile. Empty tiles exit on the
// count read (out already zeroed). Active tiles accumulate in LDS: per wave,
// read 64 bin entries (prefetching the next 64 to hide bins latency), then
// 4 sub-batches of 16 independent x-loads + LDS atomics (lane = channel,
// conflict-free banks). Final tile store is plain (one block owns the tile).
__global__ __launch_bounds__(256, 4) void gather_active(const float* __restrict__ x,
                                                        const int* __restrict__ counts,
                                                        const int* __restrict__ bins,
                                                        float* __restrict__ out) {
  __shared__ float tile[64][65];
  int bt  = blockIdx.x;                     // 0..NTILES-1
  int cnt = counts[bt];
  if (cnt == 0) return;

  int t    = threadIdx.x;
  int lane = t & 63;
  int wv   = t >> 6;                        // wave id, 0..3
  int b    = bt / VTILES;
  int v0   = (bt % VTILES) * 64;

  for (int i = t; i < 64 * 65; i += 256) ((float*)tile)[i] = 0.f;
  __syncthreads();

  int n = cnt < CAP ? cnt : CAP;
  const int* tb = bins + (size_t)bt * CAP;

  int j0 = wv * 64;
  int e  = -1;
  if (j0 + lane < n) e = tb[j0 + lane];

  while (j0 < n) {
    int jn = j0 + 256;                      // this wave's next round
    int en = -1;
    if (jn + lane < n) en = tb[jn + lane];  // prefetch next round's entries

#pragma unroll
    for (int sb = 0; sb < 4; ++sb) {
      float vals[16];
      int   vins[16];
      bool  ok[16];
#pragma unroll
      for (int k = 0; k < 16; ++k) {
        int ek  = __shfl(e, sb * 16 + k);
        ok[k]   = ek >= 0;
        vins[k] = (ek >> 19) & 63;
        int pid = ek & 0x7FFFF;
        vals[k] = ok[k] ? x[(size_t)pid * C + lane] : 0.f;   // independent loads
      }
#pragma unroll
      for (int k = 0; k < 16; ++k)
        if (ok[k]) atomicAdd(&tile[vins[k]][lane], vals[k]);
    }
    e  = en;
    j0 = jn;
  }
  __syncthreads();

  int v4 = (t & 15) * 4;
  int cq = t >> 4;                          // 0..15
  for (int k = 0; k < 4; ++k) {
    int c = cq + k * 16;
    float4 vv;
    vv.x = tile[v4 + 0][c];
    vv.y = tile[v4 + 1][c];
    vv.z = tile[v4 + 2][c];
    vv.w = tile[v4 + 3][c];
    *(float4*)(out + ((size_t)(b * C + c)) * NVOX + v0 + v4) = vv;
  }
}

// Pass 3: drain overflow list (normally empty) with direct atomics onto out.
__global__ __launch_bounds__(256) void overflow_splat(const float* __restrict__ x,
                                                      const float* __restrict__ rots,
                                                      const float* __restrict__ trans,
                                                      const float* __restrict__ intrins,
                                                      const float* __restrict__ post_rots,
                                                      const float* __restrict__ post_trans,
                                                      const int* __restrict__ counts,
                                                      const int* __restrict__ ovf,
                                                      float* __restrict__ out) {
  int n = counts[NTILES];
  if (n <= 0) return;
  if (n > NPTS) n = NPTS;

  __shared__ float smats[B * N * MAT_STRIDE];
  int t = threadIdx.x;
  if (t < B * N)
    build_mats(t, rots, trans, intrins, post_rots, post_trans, smats + t * MAT_STRIDE);
  __syncthreads();

  int lane = t & 63;
  int wid  = (blockIdx.x * 256 + t) >> 6;
  int nw   = (gridDim.x * 256) >> 6;
  for (int i = wid; i < n; i += nw) {
    int pid = ovf[i];
    int v = point_voxel(pid, smats);
    if (v < 0) continue;
    int b   = v / NVOX;
    int loc = v % NVOX;
    atomicAdd(out + ((size_t)(b * C + lane)) * NVOX + loc, x[(size_t)pid * C + lane]);
  }
}

// ---- minimal-ws fallback: direct atomics into out ----
__global__ void prep_mats(const float* __restrict__ rots,
                          const float* __restrict__ trans,
                          const float* __restrict__ intrins,
                          const float* __restrict__ post_rots,
                          const float* __restrict__ post_trans,
                          float* __restrict__ mats) {
  int i = blockIdx.x * blockDim.x + threadIdx.x;
  if (i >= B * N) return;
  build_mats(i, rots, trans, intrins, post_rots, post_trans, mats + i * MAT_STRIDE);
}

__global__ __launch_bounds__(256) void lss_splat_direct(const float* __restrict__ x,
                                                        const float* __restrict__ mats,
                                                        float* __restrict__ out) {
  int wid  = blockIdx.x * 4 + (threadIdx.x >> 6);
  if (wid >= NPTS) return;
  int lane = threadIdx.x & 63;
  int voxel = point_voxel(wid, mats);
  if (voxel < 0) return;
  int b = voxel / NVOX;
  int v = voxel % NVOX;
  float val = x[(size_t)wid * C + lane];
  size_t oidx = ((size_t)(b * C + lane)) * NVOX + v;
  atomicAdd(out + oidx, val);
}

}  // namespace

extern "C" void kernel_launch(void* const* d_in, const int* in_sizes, int n_in,
                              void* d_out, int out_size, void* d_ws, size_t ws_size,
                              hipStream_t stream) {
  const float* x          = (const float*)d_in[0];
  const float* rots       = (const float*)d_in[1];
  const float* trans      = (const float*)d_in[2];
  const float* intrins    = (const float*)d_in[3];
  const float* post_rots  = (const float*)d_in[4];
  const float* post_trans = (const float*)d_in[5];
  float* out = (float*)d_out;

  // ws layout: counts[NTILES+1] | bins[NTILES*CAP] | ovf[NPTS]
  const size_t bins_off = (((size_t)(NTILES + 1) * sizeof(int)) + 255) & ~(size_t)255;
  const size_t ovf_off  = bins_off + (size_t)NTILES * CAP * sizeof(int);
  const size_t need     = ovf_off + (size_t)NPTS * sizeof(int);

  if (ws_size >= need) {
    int* counts = (int*)d_ws;
    int* bins   = (int*)((char*)d_ws + bins_off);
    int* ovf    = (int*)((char*)d_ws + ovf_off);

    clear_counts<<<(NTILES + 1 + 255) / 256, 256, 0, stream>>>(counts);
    bin_zero<<<NPTS / 256, 256, 0, stream>>>(rots, trans, intrins, post_rots,
                                             post_trans, counts, bins, ovf,
                                             (float4*)out);
    gather_active<<<NTILES, 256, 0, stream>>>(x, counts, bins, out);
    overflow_splat<<<16, 256, 0, stream>>>(x, rots, trans, intrins, post_rots,
                                           post_trans, counts, ovf, out);
  } else {
    float* mats = (float*)d_ws;  // 4.6 KB
    hipMemsetAsync(d_out, 0, (size_t)out_size * sizeof(float), stream);
    prep_mats<<<1, 64, 0, stream>>>(rots, trans, intrins, post_rots, post_trans, mats);
    lss_splat_direct<<<(NPTS + 3) / 4, 256, 0, stream>>>(x, mats, out);
  }
}

// Round 11
// 96.487 us; speedup vs baseline: 1.4004x; 1.4004x over previous
//
#include <hip/hip_runtime.h>
#include <math.h>

namespace {

constexpr int B  = 8;
constexpr int N  = 6;
constexpr int D  = 41;
constexpr int FH = 8;    // 128/16
constexpr int FW = 22;   // 352/16
constexpr int C  = 64;
constexpr int NPTS = B * N * D * FH * FW;   // 346368 = 1353 * 256
constexpr int NX0 = 200, NX1 = 200, NX2 = 1;
constexpr int NVOX = NX0 * NX1;             // 40000 voxels per batch (gz==0)
constexpr int MAT_STRIDE = 24;
constexpr int VTILES = NVOX / 64;           // 625 tiles per batch
constexpr int NTILES = B * VTILES;          // 5000
constexpr int CHUNK  = 256;                 // entries per gather work item
constexpr int CAP    = 3840;                // bin capacity per tile (15 chunks)
constexpr int MAXCH  = CAP / CHUNK;         // 15
constexpr int OUT4   = B * C * NVOX / 4;    // 5,120,000 float4s in out
constexpr int GQBLK  = 1024;                // gather_wq grid

__device__ inline void inv3x3(const float a[9], float r[9]) {
  float c00 = a[4] * a[8] - a[5] * a[7];
  float c01 = a[5] * a[6] - a[3] * a[8];
  float c02 = a[3] * a[7] - a[4] * a[6];
  float det = a[0] * c00 + a[1] * c01 + a[2] * c02;
  float id  = 1.0f / det;
  r[0] = c00 * id;
  r[1] = (a[2] * a[7] - a[1] * a[8]) * id;
  r[2] = (a[1] * a[5] - a[2] * a[4]) * id;
  r[3] = c01 * id;
  r[4] = (a[0] * a[8] - a[2] * a[6]) * id;
  r[5] = (a[2] * a[3] - a[0] * a[5]) * id;
  r[6] = c02 * id;
  r[7] = (a[1] * a[6] - a[0] * a[7]) * id;
  r[8] = (a[0] * a[4] - a[1] * a[3]) * id;
}

__device__ inline void build_mats(int i,
                                  const float* __restrict__ rots,
                                  const float* __restrict__ trans,
                                  const float* __restrict__ intrins,
                                  const float* __restrict__ post_rots,
                                  const float* __restrict__ post_trans,
                                  float* __restrict__ o) {
#pragma clang fp contract(off)
  const float eps = 1e-6f;
  float m[9], inv_post[9], ki[9];

  for (int k = 0; k < 9; ++k) m[k] = post_rots[i * 9 + k];
  m[0] += eps; m[4] += eps; m[8] += eps;
  inv3x3(m, inv_post);

  for (int k = 0; k < 9; ++k) m[k] = intrins[i * 9 + k];
  m[0] += eps; m[4] += eps; m[8] += eps;
  inv3x3(m, ki);

  for (int k = 0; k < 9; ++k) o[k] = inv_post[k];
  for (int r = 0; r < 3; ++r)
    for (int c = 0; c < 3; ++c)
      o[9 + r * 3 + c] = rots[i * 9 + r * 3 + 0] * ki[0 * 3 + c]
                       + rots[i * 9 + r * 3 + 1] * ki[1 * 3 + c]
                       + rots[i * 9 + r * 3 + 2] * ki[2 * 3 + c];
  for (int k = 0; k < 3; ++k) o[18 + k] = trans[i * 3 + k];
  for (int k = 0; k < 3; ++k) o[21 + k] = post_trans[i * 3 + k];
}

__device__ inline int point_voxel(int wid, const float* __restrict__ mats) {
#pragma clang fp contract(off)
  int t  = wid;
  int w  = t % FW;  t /= FW;
  int h  = t % FH;  t /= FH;
  int dd = t % D;   t /= D;
  int n  = t % N;
  int b  = t / N;

  const float* M = mats + (b * N + n) * MAT_STRIDE;

  float u   = (float)w * (351.0f / 21.0f);
  float v   = (float)h * (127.0f / 7.0f);
  float dep = 4.0f + (float)dd;

  float p0 = u - M[21], p1 = v - M[22], p2 = dep - M[23];

  float q0 = M[0] * p0 + M[1] * p1 + M[2] * p2;
  float q1 = M[3] * p0 + M[4] * p1 + M[5] * p2;
  float q2 = M[6] * p0 + M[7] * p1 + M[8] * p2;

  float sd;
  if (fabsf(q2) < 1e-6f) {
    float t2 = q2 + 1e-6f;
    float s  = (t2 > 0.0f) ? 1.0f : ((t2 < 0.0f) ? -1.0f : 0.0f);
    sd = 1e-6f * s;
  } else {
    sd = q2;
  }
  float r0 = q0 * sd, r1 = q1 * sd, r2 = sd;

  float g0 = (M[9]  * r0 + M[10] * r1 + M[11] * r2) + M[18];
  float g1 = (M[12] * r0 + M[13] * r1 + M[14] * r2) + M[19];
  float g2 = (M[15] * r0 + M[16] * r1 + M[17] * r2) + M[20];

  float gnx = (g0 + 50.0f) / 0.5f;
  float gny = (g1 + 50.0f) / 0.5f;
  float gnz = (g2 + 10.0f) / 20.0f;
  int gx = (int)gnx;
  int gy = (int)gny;
  int gz = (int)gnz;

  if (gx < 0 || gx >= NX0 || gy < 0 || gy >= NX1 || gz < 0 || gz >= NX2)
    return -1;
  return b * NVOX + gx * NX1 + gy;   // global voxel id (gz == 0)
}

// Pass 0: clear counts[NTILES] (per-tile), counts[NTILES]=overflow ctr,
// counts[NTILES+1]=work-queue length.
__global__ __launch_bounds__(256) void clear_counts(int* __restrict__ counts) {
  int i = blockIdx.x * 256 + threadIdx.x;
  if (i < NTILES + 2) counts[i] = 0;
}

// Pass 1: bin kept points by tile AND zero `out` via a linear float4 stream.
__global__ __launch_bounds__(256) void bin_zero(const float* __restrict__ rots,
                                                const float* __restrict__ trans,
                                                const float* __restrict__ intrins,
                                                const float* __restrict__ post_rots,
                                                const float* __restrict__ post_trans,
                                                int* __restrict__ counts,
                                                int* __restrict__ bins,
                                                int* __restrict__ ovf,
                                                float4* __restrict__ out4) {
  __shared__ float smats[B * N * MAT_STRIDE];
  int t = threadIdx.x;
  if (t < B * N)
    build_mats(t, rots, trans, intrins, post_rots, post_trans, smats + t * MAT_STRIDE);
  __syncthreads();

  int pid = blockIdx.x * 256 + t;           // NPTS is a multiple of 256
  int v = point_voxel(pid, smats);
  if (v >= 0) {
    int bt  = v >> 6;                       // tile id (NVOX % 64 == 0)
    int vin = v & 63;
    int idx = atomicAdd(&counts[bt], 1);
    if (idx < CAP) {
      bins[(size_t)bt * CAP + idx] = pid | (vin << 19);
    } else {
      int o = atomicAdd(&counts[NTILES], 1);
      if (o < NPTS) ovf[o] = pid;
    }
  }

  const float4 z = make_float4(0.f, 0.f, 0.f, 0.f);
  for (int i = pid; i < OUT4; i += NPTS) out4[i] = z;
}

// Pass 2: build the work queue — tiles with cnt>0 push ceil(n/CHUNK) items.
// Item packs tile id (13b) | chunk idx (<<13).
__global__ __launch_bounds__(256) void build_queue(int* __restrict__ counts,
                                                   int* __restrict__ wq) {
  int i = blockIdx.x * 256 + threadIdx.x;
  if (i >= NTILES) return;
  int n = counts[i];
  if (n <= 0) return;
  if (n > CAP) n = CAP;
  int nc = (n + CHUNK - 1) / CHUNK;
  int base = atomicAdd(&counts[NTILES + 1], nc);
  for (int k = 0; k < nc; ++k) wq[base + k] = i | ((k) << 13);
}

// Pass 3: chunk-parallel gather. 1024 blocks grid-stride over ~hundreds of
// work items; each item = up to 256 bin entries of one tile. Accumulate in a
// LDS tile (lane = channel, conflict-free). Single-chunk tiles plain-store the
// full tile; multi-chunk tiles atomicAdd only the touched voxel rows
// (contiguous addresses per channel) onto the pre-zeroed output.
__global__ __launch_bounds__(256, 4) void gather_wq(const float* __restrict__ x,
                                                    const int* __restrict__ counts,
                                                    const int* __restrict__ bins,
                                                    const int* __restrict__ wq,
                                                    float* __restrict__ out) {
  __shared__ float tile[64][65];
  __shared__ int touched[64];
  int t    = threadIdx.x;
  int lane = t & 63;
  int wv   = t >> 6;                        // 0..3

  int nwork = counts[NTILES + 1];

  for (int it = blockIdx.x; it < nwork; it += GQBLK) {
    int item  = wq[it];
    int bt    = item & 0x1FFF;
    int chunk = item >> 13;
    int cnt   = counts[bt];
    int n     = cnt < CAP ? cnt : CAP;
    int start = chunk * CHUNK;
    int end   = start + CHUNK < n ? start + CHUNK : n;
    bool single = (n <= CHUNK);             // this block owns the whole tile

    int b  = bt / VTILES;
    int v0 = (bt % VTILES) * 64;

    // zero LDS tile + touched flags
    for (int i = t; i < 64 * 65; i += 256) ((float*)tile)[i] = 0.f;
    if (t < 64) touched[t] = 0;
    __syncthreads();

    // this wave's 64 entries (one coalesced read), then 4 sub-batches of 16
    int j = start + wv * 64 + lane;
    int e = (j < end) ? bins[(size_t)bt * CAP + j] : -1;

#pragma unroll
    for (int sb = 0; sb < 4; ++sb) {
      float vals[16];
      int   vins[16];
      bool  ok[16];
#pragma unroll
      for (int k = 0; k < 16; ++k) {
        int ek  = __shfl(e, sb * 16 + k);
        ok[k]   = ek >= 0;                       // wave-uniform
        vins[k] = (ek >> 19) & 63;
        int pid = ok[k] ? (ek & 0x7FFFF) : 0;    // clamp: always issue load
        vals[k] = x[(size_t)pid * C + lane];     // 16 independent loads
      }
#pragma unroll
      for (int k = 0; k < 16; ++k) {
        if (ok[k]) {
          atomicAdd(&tile[vins[k]][lane], vals[k]);
          if (lane == 0) touched[vins[k]] = 1;
        }
      }
    }
    __syncthreads();

    if (single) {
      // plain store of the whole 64x64 tile, voxel-contiguous float4s
      int v4 = (t & 15) * 4;
      int cq = t >> 4;                      // 0..15
      for (int k = 0; k < 4; ++k) {
        int c = cq + k * 16;
        float4 vv;
        vv.x = tile[v4 + 0][c];
        vv.y = tile[v4 + 1][c];
        vv.z = tile[v4 + 2][c];
        vv.w = tile[v4 + 3][c];
        *(float4*)(out + ((size_t)(b * C + c)) * NVOX + v0 + v4) = vv;
      }
    } else {
      // atomic add of touched rows only; lane = voxel -> contiguous addresses
      bool mine = touched[lane] != 0;
#pragma unroll
      for (int k = 0; k < 16; ++k) {
        int c = wv * 16 + k;
        if (mine)
          atomicAdd(out + ((size_t)(b * C + c)) * NVOX + v0 + lane, tile[lane][c]);
      }
    }
    __syncthreads();                        // LDS reuse guard before next item
  }
}

// Pass 4: drain overflow list (normally empty). Overflow tiles are always
// multi-chunk (cnt > CAP > CHUNK), so gather used atomics there -- compatible.
__global__ __launch_bounds__(256) void overflow_splat(const float* __restrict__ x,
                                                      const float* __restrict__ rots,
                                                      const float* __restrict__ trans,
                                                      const float* __restrict__ intrins,
                                                      const float* __restrict__ post_rots,
                                                      const float* __restrict__ post_trans,
                                                      const int* __restrict__ counts,
                                                      const int* __restrict__ ovf,
                                                      float* __restrict__ out) {
  int n = counts[NTILES];
  if (n <= 0) return;
  if (n > NPTS) n = NPTS;

  __shared__ float smats[B * N * MAT_STRIDE];
  int t = threadIdx.x;
  if (t < B * N)
    build_mats(t, rots, trans, intrins, post_rots, post_trans, smats + t * MAT_STRIDE);
  __syncthreads();

  int lane = t & 63;
  int wid  = (blockIdx.x * 256 + t) >> 6;
  int nw   = (gridDim.x * 256) >> 6;
  for (int i = wid; i < n; i += nw) {
    int pid = ovf[i];
    int v = point_voxel(pid, smats);
    if (v < 0) continue;
    int b   = v / NVOX;
    int loc = v % NVOX;
    atomicAdd(out + ((size_t)(b * C + lane)) * NVOX + loc, x[(size_t)pid * C + lane]);
  }
}

// ---- minimal-ws fallback: direct atomics into out ----
__global__ void prep_mats(const float* __restrict__ rots,
                          const float* __restrict__ trans,
                          const float* __restrict__ intrins,
                          const float* __restrict__ post_rots,
                          const float* __restrict__ post_trans,
                          float* __restrict__ mats) {
  int i = blockIdx.x * blockDim.x + threadIdx.x;
  if (i >= B * N) return;
  build_mats(i, rots, trans, intrins, post_rots, post_trans, mats + i * MAT_STRIDE);
}

__global__ __launch_bounds__(256) void lss_splat_direct(const float* __restrict__ x,
                                                        const float* __restrict__ mats,
                                                        float* __restrict__ out) {
  int wid  = blockIdx.x * 4 + (threadIdx.x >> 6);
  if (wid >= NPTS) return;
  int lane = threadIdx.x & 63;
  int voxel = point_voxel(wid, mats);
  if (voxel < 0) return;
  int b = voxel / NVOX;
  int v = voxel % NVOX;
  float val = x[(size_t)wid * C + lane];
  size_t oidx = ((size_t)(b * C + lane)) * NVOX + v;
  atomicAdd(out + oidx, val);
}

}  // namespace

extern "C" void kernel_launch(void* const* d_in, const int* in_sizes, int n_in,
                              void* d_out, int out_size, void* d_ws, size_t ws_size,
                              hipStream_t stream) {
  const float* x          = (const float*)d_in[0];
  const float* rots       = (const float*)d_in[1];
  const float* trans      = (const float*)d_in[2];
  const float* intrins    = (const float*)d_in[3];
  const float* post_rots  = (const float*)d_in[4];
  const float* post_trans = (const float*)d_in[5];
  float* out = (float*)d_out;

  // ws layout: counts[NTILES+2] | bins[NTILES*CAP] (76.8MB) | ovf[NPTS] | wq[NTILES*MAXCH]
  const size_t bins_off = (((size_t)(NTILES + 2) * sizeof(int)) + 255) & ~(size_t)255;
  const size_t ovf_off  = bins_off + (size_t)NTILES * CAP * sizeof(int);
  const size_t wq_off   = (ovf_off + (size_t)NPTS * sizeof(int) + 255) & ~(size_t)255;
  const size_t need     = wq_off + (size_t)NTILES * MAXCH * sizeof(int);

  if (ws_size >= need) {
    int* counts = (int*)d_ws;
    int* bins   = (int*)((char*)d_ws + bins_off);
    int* ovf    = (int*)((char*)d_ws + ovf_off);
    int* wq     = (int*)((char*)d_ws + wq_off);

    clear_counts<<<(NTILES + 2 + 255) / 256, 256, 0, stream>>>(counts);
    bin_zero<<<NPTS / 256, 256, 0, stream>>>(rots, trans, intrins, post_rots,
                                             post_trans, counts, bins, ovf,
                                             (float4*)out);
    build_queue<<<(NTILES + 255) / 256, 256, 0, stream>>>(counts, wq);
    gather_wq<<<GQBLK, 256, 0, stream>>>(x, counts, bins, wq, out);
    overflow_splat<<<16, 256, 0, stream>>>(x, rots, trans, intrins, post_rots,
                                           post_trans, counts, ovf, out);
  } else {
    float* mats = (float*)d_ws;  // 4.6 KB
    hipMemsetAsync(d_out, 0, (size_t)out_size * sizeof(float), stream);
    prep_mats<<<1, 64, 0, stream>>>(rots, trans, intrins, post_rots, post_trans, mats);
    lss_splat_direct<<<(NPTS + 3) / 4, 256, 0, stream>>>(x, mats, out);
  }
}